// Round 6
// baseline (758.962 us; speedup 1.0000x reference)
//
#include <hip/hip_runtime.h>
#include <stdint.h>

#define E_ 3
#define C_ 2
#define N_ 2048
#define B_ 64
#define T_ 50
#define WIN_ 256
#define WOUT_ 256
#define U_ 512
#define BT_ (B_*T_)
#define BTP_ 3328

typedef unsigned short u16;
typedef unsigned int u32;
typedef __bf16 bf16x8 __attribute__((ext_vector_type(8)));
typedef float f32x4 __attribute__((ext_vector_type(4)));

#define NN_ (2048LL*2048LL)

__device__ __forceinline__ float bf2f(u16 u){
  u32 x = ((u32)u) << 16; return __builtin_bit_cast(float, x);
}
__device__ __forceinline__ u16 f2bf(float f){
  u32 x = __builtin_bit_cast(u32, f);
  u32 r = (x + 0x7fffu + ((x >> 16) & 1u)) >> 16;
  return (u16)r;
}

__device__ __forceinline__ void gload16(const u16* g, u16* l){
  __builtin_amdgcn_global_load_lds((const __attribute__((address_space(1))) u32*)g,
                                   (__attribute__((address_space(3))) u32*)l, 16, 0, 0);
}

// ---------------- softmax filters: filt[(fi*C+c)*E+e] ----------------
__global__ void k_filters(const float* __restrict__ w1, const float* __restrict__ w2,
                          const float* __restrict__ w3, float* __restrict__ filt){
  const int t = threadIdx.x;
  if(t >= 3*C_) return;
  const int fi = t / C_, c = t % C_;
  const float* w = (fi==0) ? w1 : ((fi==1) ? w2 : w3);
  float v[E_]; float mx = -3.4e38f;
  for(int e=0;e<E_;e++){ v[e] = w[c*E_+e]; mx = fmaxf(mx, v[e]); }
  float s = 0.f;
  for(int e=0;e<E_;e++){ v[e] = expf(v[e]-mx); s += v[e]; }
  for(int e=0;e<E_;e++) filt[(fi*C_+c)*E_ + e] = v[e]/s;
}

// ---------------- fused combine: HA (direct) + HBt (transposed), A read ONCE ----------------
__global__ void k_combineAll(const float* __restrict__ A, const float* __restrict__ filt,
                             u16* __restrict__ HA, u16* __restrict__ HBt){
  __shared__ float te[3][32][33];
  const int ti = blockIdx.x, tj = blockIdx.y;
  const int x = threadIdx.x, y0 = threadIdx.y;
  #pragma unroll
  for(int i=0;i<4;i++){
    const int y = y0 + i*8;
    const long base = (long)(tj*32+y)*N_ + ti*32 + x;
    const float a0 = A[0*NN_+base], a1 = A[1*NN_+base], a2 = A[2*NN_+base];
    te[0][y][x]=a0; te[1][y][x]=a1; te[2][y][x]=a2;
    #pragma unroll
    for(int c=0;c<C_;c++)
      HA[c*NN_ + base] = f2bf(filt[c*E_]*a0 + filt[c*E_+1]*a1 + filt[c*E_+2]*a2);
  }
  __syncthreads();
  #pragma unroll
  for(int i=0;i<4;i++){
    const int y = y0 + i*8;
    const long ob = (long)(ti*32+y)*N_ + tj*32 + x;
    const float a0=te[0][x][y], a1=te[1][x][y], a2=te[2][x][y];
    #pragma unroll
    for(int c=0;c<C_;c++)
      HBt[c*NN_+ob] = f2bf(filt[(C_+c)*E_]*a0 + filt[(C_+c)*E_+1]*a1 + filt[(C_+c)*E_+2]*a2);
  }
}

// ---------------- HB2t both channels, one pass over A ----------------
__global__ void k_combineT2(const float* __restrict__ A, const float* __restrict__ f,
                            u16* __restrict__ outp){
  __shared__ float te[3][32][33];
  const int ti = blockIdx.x, tj = blockIdx.y;
  const int x = threadIdx.x, y0 = threadIdx.y;
  #pragma unroll
  for(int i=0;i<4;i++){
    const int y = y0 + i*8;
    const long base = (long)(tj*32+y)*N_ + ti*32 + x;
    te[0][y][x]=A[0*NN_+base]; te[1][y][x]=A[1*NN_+base]; te[2][y][x]=A[2*NN_+base];
  }
  __syncthreads();
  #pragma unroll
  for(int i=0;i<4;i++){
    const int y = y0 + i*8;
    const long ob = (long)(ti*32+y)*N_ + tj*32 + x;
    const float a0=te[0][x][y], a1=te[1][x][y], a2=te[2][x][y];
    #pragma unroll
    for(int c=0;c<C_;c++)
      outp[c*NN_+ob] = f2bf(f[c*E_]*a0 + f[c*E_+1]*a1 + f[c*E_+2]*a2);
  }
}

// ---------------- MFMA GEMM: OUT[i][j] = sum_k A[i][k]*B[j][k] ----------------
template<int MODE>
__global__ __launch_bounds__(256) void gemm_bt(
    const u16* __restrict__ Ag, const u16* __restrict__ Bg, void* __restrict__ Cg,
    int K, int ldc, long sA, long sB, long sC,
    const float* __restrict__ disv, int sDis, const float* __restrict__ bias)
{
  __shared__ u16 At[128*32];
  __shared__ u16 Bt[128*32];
  const int tid = threadIdx.x;
  const int w = tid >> 6, l = tid & 63;
  const int z = blockIdx.z;
  const u16* Ab = Ag + (long)z*sA;
  const u16* Bb = Bg + (long)z*sB;
  const int rowBase = blockIdx.y*128;
  const int colBase = blockIdx.x*128;

  f32x4 acc[4][4];
  #pragma unroll
  for(int i=0;i<4;i++)
    #pragma unroll
    for(int j=0;j<4;j++)
      acc[i][j] = f32x4{0.f,0.f,0.f,0.f};

  const int wr = w >> 1, wc = w & 1;
  const int arow0 = (w*2+0)*16 + (l>>2);
  const int arow1 = (w*2+1)*16 + (l>>2);
  const int kc = (((l&3) ^ ((l>>2)&3)))*8;
  const int frow = l & 15;
  const int fkc = l >> 4;

  const int nk = K >> 5;
  for(int kt=0; kt<nk; ++kt){
    const int k0 = kt << 5;
    gload16(Ab + (long)(rowBase+arow0)*K + k0 + kc, &At[(w*2+0)*512]);
    gload16(Ab + (long)(rowBase+arow1)*K + k0 + kc, &At[(w*2+1)*512]);
    gload16(Bb + (long)(colBase+arow0)*K + k0 + kc, &Bt[(w*2+0)*512]);
    gload16(Bb + (long)(colBase+arow1)*K + k0 + kc, &Bt[(w*2+1)*512]);
    __syncthreads();
    bf16x8 af[4], bfv[4];
    #pragma unroll
    for(int m=0;m<4;m++){
      const int rr = wr*64 + m*16 + frow;
      af[m] = *(const bf16x8*)&At[rr*32 + ((fkc ^ (rr&3))<<3)];
    }
    #pragma unroll
    for(int n=0;n<4;n++){
      const int rr = wc*64 + n*16 + frow;
      bfv[n] = *(const bf16x8*)&Bt[rr*32 + ((fkc ^ (rr&3))<<3)];
    }
    #pragma unroll
    for(int m=0;m<4;m++)
      #pragma unroll
      for(int n=0;n<4;n++)
        acc[m][n] = __builtin_amdgcn_mfma_f32_16x16x32_bf16(af[m], bfv[n], acc[m][n], 0, 0, 0);
    __syncthreads();
  }

  #pragma unroll
  for(int m=0;m<4;m++){
    const int row0 = rowBase + wr*64 + m*16 + (l>>4)*4;
    #pragma unroll
    for(int n=0;n<4;n++){
      const int col = colBase + wc*64 + n*16 + (l&15);
      #pragma unroll
      for(int r=0;r<4;r++){
        const float v = acc[m][n][r];
        if(MODE==1){
          ((u16*)Cg)[z*sC + (long)(row0+r)*ldc + col] = f2bf(v);
        } else if(MODE==2){
          float o = disv[z*(long)sDis + row0 + r]*v + bias[col];
          o = o > 0.f ? o : 0.f;
          ((u16*)Cg)[z*sC + (long)(row0+r)*ldc + col] = f2bf(o);
        } else if(MODE==3){
          ((float*)Cg)[z*sC + (long)(row0+r)*ldc + col] = v + bias[col];
        } else if(MODE==4){
          const int row = row0 + r;
          if(row < BT_){
            const int bb = row/50, tt = row - bb*50;
            ((float*)Cg)[((long)tt*2048 + col)*64 + bb] = v + bias[col];
          }
        }
      }
    }
  }
}

// ---------------- column-degree partial sums ----------------
__global__ void k_degpart(const u16* __restrict__ H, float* __restrict__ partial){
  const int c = blockIdx.z;
  const int col = blockIdx.x*256 + threadIdx.x;
  const int r0 = blockIdx.y*128;
  const u16* Hc = H + c*NN_;
  float s = 0.f;
  #pragma unroll 4
  for(int r=0;r<128;r++) s += bf2f(Hc[(long)(r0+r)*N_ + col]);
  partial[((long)c*16 + blockIdx.y)*N_ + col] = s;
}

// ---------------- dinv[c][m] = 1/(colsum - diag), guarded ----------------
__global__ void k_dinv(const u16* __restrict__ H, const float* __restrict__ partial,
                       float* __restrict__ dinvb){
  const int i = blockIdx.x*256 + threadIdx.x;
  const int c = i >> 11, m = i & (N_-1);
  float s = 0.f;
  #pragma unroll
  for(int p=0;p<16;p++) s += partial[((long)c*16 + p)*N_ + m];
  s -= bf2f(H[c*NN_ + (long)m*N_ + m]);
  dinvb[i] = s > 0.f ? 1.f/s : 0.f;
}

// ---------------- H[j][i] = (j==i) ? 0 : H*dinv[i] ----------------
__global__ void k_colscale(u16* __restrict__ H, const float* __restrict__ dinvb){
  const long i = (long)blockIdx.x*256 + threadIdx.x;
  const int c = blockIdx.y;
  const int j = (int)(i >> 11), ii = (int)(i & (N_-1));
  const long idx = c*NN_ + i;
  const float v = (j==ii) ? 0.f : bf2f(H[idx])*dinvb[c*N_ + ii];
  H[idx] = f2bf(v);
}

// ---------------- dis[c][j] = rsqrt(1 + rowsum(H2t[c][j][:])) ----------------
__global__ void k_gcnprep(const u16* __restrict__ H2t, float* __restrict__ disv){
  const int c = blockIdx.y, j = blockIdx.x;
  const u16* r = H2t + (c*(long)N_ + j)*N_;
  float s = 0.f;
  for(int i=threadIdx.x;i<N_;i+=256) s += bf2f(r[i]);
  __shared__ float red[256];
  red[threadIdx.x] = s;
  __syncthreads();
  for(int st=128; st>0; st>>=1){
    if(threadIdx.x < st) red[threadIdx.x] += red[threadIdx.x+st];
    __syncthreads();
  }
  if(threadIdx.x==0){
    const float deg = red[0] + 1.f;
    disv[c*N_ + j] = deg > 0.f ? rsqrtf(deg) : 0.f;
  }
}

// ---------------- Pd[c][j][i] = (H2t + I) * dis[i] ----------------
__global__ void k_pd(const u16* __restrict__ H2t, const float* __restrict__ disv,
                     u16* __restrict__ Pd){
  const long i = (long)blockIdx.x*256 + threadIdx.x;
  const int c = blockIdx.y;
  const int j = (int)(i >> 11);
  const int ii = (int)(i & (N_-1));
  const long idx = c*NN_ + i;
  const float v = bf2f(H2t[idx]) + (ii==j ? 1.f : 0.f);
  Pd[idx] = f2bf(v*disv[c*N_ + ii]);
}

// ---------------- transpose f32 in[R][Cc] -> bf16 out[Cc][R] ----------------
__global__ void k_transpose(const float* __restrict__ in, u16* __restrict__ out,
                            int R, int Cc){
  __shared__ float tt[32][33];
  const int ti = blockIdx.x, tj = blockIdx.y;
  const int x = threadIdx.x, y0 = threadIdx.y;
  #pragma unroll
  for(int i=0;i<4;i++){
    const int y = y0 + i*8;
    tt[y][x] = in[(long)(tj*32+y)*Cc + ti*32 + x];
  }
  __syncthreads();
  #pragma unroll
  for(int i=0;i<4;i++){
    const int y = y0 + i*8;
    out[(long)(ti*32+y)*R + tj*32 + x] = f2bf(tt[x][y]);
  }
}

// ---------------- cast f32 -> bf16 ----------------
__global__ void k_cast(const float* __restrict__ in, u16* __restrict__ out){
  const long i = (long)blockIdx.x*256 + threadIdx.x;
  out[i] = f2bf(in[i]);
}

// ---------------- bsum = bih + bhh; zero sync counters ----------------
__global__ void k_bias(const float* __restrict__ bih, const float* __restrict__ bhh,
                       float* __restrict__ bsum, u32* __restrict__ syncv){
  const int i = blockIdx.x*256 + threadIdx.x;
  bsum[i] = bih[i] + bhh[i];
  if(i < 64) syncv[i] = 0;
}

// ---------------- basket max-pool via active list ----------------
__global__ void k_pool(const float* __restrict__ seqs, const float* __restrict__ X_,
                       u16* __restrict__ bs){
  const int t = blockIdx.x, b = blockIdx.y;
  const float* mask = seqs + ((long)b*T_ + t)*N_;
  const int f = threadIdx.x;
  __shared__ int list[N_];
  __shared__ int cnt;
  if(f==0) cnt = 0;
  __syncthreads();
  for(int n0=f; n0<N_; n0+=256){
    if(mask[n0] > 0.f){
      int p = atomicAdd(&cnt, 1);
      list[p] = n0;
    }
  }
  __syncthreads();
  const int m = cnt;
  float mx = -3.4e38f;
  for(int i=0;i<m;i++)
    mx = fmaxf(mx, X_[(long)list[i]*WOUT_ + f]);
  bs[((long)b*T_ + t)*WOUT_ + f] = f2bf(m>0 ? mx : 0.f);
}

__global__ void k_zeropad(u16* __restrict__ bs){
  const int i = blockIdx.x*256 + threadIdx.x;
  bs[(long)BT_*WOUT_ + i] = 0;
}

// ---------------- pack Whh for k_lstm_all ----------------
__global__ void k_packWhh2(const float* __restrict__ Whh, u16* __restrict__ P){
  const long idx = (long)blockIdx.x*256 + threadIdx.x;
  const int e  = (int)(idx & 511);
  const int lr = (int)((idx >> 9) & 63);
  const int g  = (int)(idx >> 15);
  const int gam = lr & 3, ui = lr >> 2;
  const int grow = gam*512 + g*16 + ui;
  const int k = e ^ ((lr & 7) << 3);
  P[idx] = f2bf(Whh[(long)grow*512 + k]);
}

// ---------------- Hbuf init ----------------
__global__ void k_hinit(const float* __restrict__ h0, u16* __restrict__ Hb){
  const int idx = blockIdx.x*256 + threadIdx.x;
  const int b = idx >> 9, u = idx & 511;
  Hb[(b << 9) + (u ^ ((b & 7) << 3))] = f2bf(h0[idx]);
}

// ---------------- persistent LSTM v2: Gxt prefetch + slim barrier ----------------
__global__ __launch_bounds__(256) void k_lstm_all(
    const u16* __restrict__ WhhB, const float* __restrict__ Gxt,
    const float* __restrict__ c0v, const int* __restrict__ seqlen,
    u16* __restrict__ Hglob, u32* __restrict__ syncv, float* __restrict__ act)
{
  __shared__ u16 Wl[64*512];
  __shared__ u16 Hl[64*512];
  const int g = blockIdx.x, tid = threadIdx.x;
  const int w = tid >> 6, l = tid & 63;
  const u16* Wsrc = WhhB + (long)g*(64*512);
  #pragma unroll
  for(int it=0; it<16; ++it){
    const int ch = it*4 + w;
    gload16(Wsrc + ch*512 + l*8, &Wl[ch*512]);
  }
  const int frow = l & 15, fkc = l >> 4;
  const int lr = w*16 + frow;
  const int ui = w*4 + (l>>4);
  const int ug = g*16 + ui;
  float cst[4];
  int sl[4];
  #pragma unroll
  for(int n=0;n<4;n++){
    const int b = n*16 + (l&15);
    cst[n] = c0v[b*U_ + ug];
    sl[n] = seqlen[b] - 1;
  }

  for(int t=0; t<T_; ++t){
    // 1) issue Gxt(t) register loads early — in flight across stage+sync+MFMA
    const float* gx = Gxt + (long)t*2048*64;
    float gxv[4][4];
    #pragma unroll
    for(int n=0;n<4;n++){
      const int b = n*16 + (l&15);
      #pragma unroll
      for(int q=0;q<4;q++)
        gxv[n][q] = gx[(q*U_+ug)*64 + b];
    }
    // 2) stage H_t into LDS
    const u16* Hin = Hglob + (t&1)*32768;
    #pragma unroll
    for(int it=0; it<16; ++it){
      const int ch = it*4 + w;
      gload16(Hin + ch*512 + l*8, &Hl[ch*512]);
    }
    __syncthreads();    // drains Hl writes (and gxv loads)

    // 3) gates = Whh-slice @ H
    f32x4 acc[4];
    #pragma unroll
    for(int n=0;n<4;n++) acc[n] = f32x4{0.f,0.f,0.f,0.f};
    #pragma unroll
    for(int kk=0; kk<16; ++kk){
      const int ke = kk*32 + fkc*8;
      bf16x8 a = *(const bf16x8*)&Wl[lr*512 + (ke ^ ((lr&7)<<3))];
      #pragma unroll
      for(int n=0;n<4;n++){
        const int b = n*16 + frow;
        bf16x8 bb = *(const bf16x8*)&Hl[b*512 + (ke ^ ((b&7)<<3))];
        acc[n] = __builtin_amdgcn_mfma_f32_16x16x32_bf16(a, bb, acc[n], 0, 0, 0);
      }
    }

    // 4) activations + h/c update + stores (gxv already resident)
    u16* Hout = Hglob + ((t+1)&1)*32768;
    #pragma unroll
    for(int n=0;n<4;n++){
      const int b = n*16 + (l&15);
      const float a0 = acc[n][0] + gxv[n][0];
      const float a1 = acc[n][1] + gxv[n][1];
      const float a2 = acc[n][2] + gxv[n][2];
      const float a3 = acc[n][3] + gxv[n][3];
      const float ig = 1.f/(1.f + expf(-a0));
      const float fg = 1.f/(1.f + expf(-a1));
      const float gg = tanhf(a2);
      const float og = 1.f/(1.f + expf(-a3));
      const float c = fg*cst[n] + ig*gg;
      const float h = og*tanhf(c);
      cst[n] = c;
      Hout[(b << 9) + (ug ^ ((b & 7) << 3))] = f2bf(h);
      if(sl[n] == t) act[b*U_ + ug] = h;
    }
    if(t == T_-1) break;             // no one consumes h_T
    __syncthreads();                 // drain all waves' stores (vmcnt 0 before barrier)
    if(tid == 0)
      __hip_atomic_fetch_add(&syncv[t], 1u, __ATOMIC_ACQ_REL, __HIP_MEMORY_SCOPE_AGENT);
    if(l == 0){                      // each wave's lane0 spins; wave exits independently
      while(__hip_atomic_load(&syncv[t], __ATOMIC_ACQUIRE, __HIP_MEMORY_SCOPE_AGENT) < 32u){
        __builtin_amdgcn_s_sleep(1);
      }
    }
    // waves proceed straight to next-step stage issue; block-wide __syncthreads
    // before Hl reads provides the intra-block ordering.
  }
}

// ---------------- out[b][n] = sigmoid(actual[b] . sWt[:,n])  (f32 out) ----------------
__global__ void k_score(const float* __restrict__ actual, const u16* __restrict__ sWt,
                        float* __restrict__ out){
  const int n = blockIdx.x*256 + threadIdx.x;
  const int b = blockIdx.y;
  const float* ab = actual + (long)b*U_;
  float s = 0.f;
  for(int uu=0; uu<U_; uu++) s += ab[uu]*bf2f(sWt[(long)uu*N_ + n]);
  out[(long)b*N_ + n] = 1.f/(1.f + expf(-s));
}

extern "C" void kernel_launch(void* const* d_in, const int* in_sizes, int n_in,
                              void* d_out, int out_size, void* d_ws, size_t ws_size,
                              hipStream_t stream){
  (void)in_sizes; (void)n_in; (void)out_size; (void)ws_size;
  const float* A      = (const float*)d_in[0];
  const float* X      = (const float*)d_in[1];
  const float* seqs   = (const float*)d_in[2];
  const int*   seqlen = (const int*)d_in[3];
  const float* h0     = (const float*)d_in[4];
  const float* c0     = (const float*)d_in[5];
  const float* gtw1   = (const float*)d_in[6];
  const float* gtw2   = (const float*)d_in[7];
  const float* gtw3   = (const float*)d_in[8];
  const float* gcnW   = (const float*)d_in[9];
  const float* gcnB   = (const float*)d_in[10];
  const float* lin1W  = (const float*)d_in[11];
  const float* lin1B  = (const float*)d_in[12];
  const float* Wih    = (const float*)d_in[13];
  const float* Whh    = (const float*)d_in[14];
  const float* bihp   = (const float*)d_in[15];
  const float* bhhp   = (const float*)d_in[16];
  const float* scoreW = (const float*)d_in[17];

  char* ws = (char*)d_ws;
  u16* buf0 = (u16*)(ws + 0);
  u16* buf1 = (u16*)(ws + 16777216);
  u16* buf2 = (u16*)(ws + 33554432);
  char* S0  = ws + 50331648;
  float* filt  = (float*)(S0 + 0);
  float* disv  = (float*)(S0 + 1024);
  u16*  Wt     = (u16*) (S0 + 17408);
  u16*  XWt    = (u16*) (S0 + 148480);
  u16*  catb   = (u16*) (S0 + 1197056);
  u16*  l1Wt   = (u16*) (S0 + 3294208);
  float* Xo    = (float*)(S0 + 3556352);
  u16*  bs     = (u16*) (S0 + 5653504);
  float* act   = (float*)(S0 + 7357440);
  u16*  sWt    = (u16*) (S0 + 7488512);
  u16*  WhhB   = (u16*) (S0 + 9585664);
  u16*  Xbf    = (u16*) (S0 + 11682816);
  u16*  Wihbf  = (u16*) (S0 + 12731392);
  float* bsum  = (float*)(S0 + 13779968);
  u16*  Hglob  = (u16*) (S0 + 13788160);
  u32*  syncv  = (u32*) (S0 + 13919232);
  float* degp  = (float*)(S0 + 14050304);
  float* dinvb = (float*)(S0 + 14312448);
  u16* HA   = buf0;
  u16* HBt  = buf1;
  u16* Hb   = buf2;
  u16* HB2t = buf0;
  u16* H2t  = buf1;
  u16* Pd   = buf1;
  float* Gxt = (float*)ws;

  k_filters<<<1, 64, 0, stream>>>(gtw1, gtw2, gtw3, filt);
  k_combineAll<<<dim3(N_/32, N_/32), dim3(32,8), 0, stream>>>(A, filt, HA, HBt);
  k_transpose<<<dim3(WOUT_/32, WIN_/32), dim3(32,8), 0, stream>>>(gcnW, Wt, WIN_, WOUT_);
  k_transpose<<<dim3(WOUT_/32, (C_*WOUT_)/32), dim3(32,8), 0, stream>>>(lin1W, l1Wt, C_*WOUT_, WOUT_);
  k_transpose<<<dim3(U_/32, N_/32), dim3(32,8), 0, stream>>>(scoreW, sWt, N_, U_);
  k_cast<<<dim3((N_*WIN_)/256), 256, 0, stream>>>(X, Xbf);
  k_cast<<<dim3((4*U_*WOUT_)/256), 256, 0, stream>>>(Wih, Wihbf);
  k_bias<<<dim3((4*U_)/256), 256, 0, stream>>>(bihp, bhhp, bsum, syncv);
  gemm_bt<1><<<dim3(16,16,C_), 256, 0, stream>>>(HA, HBt, Hb, N_, N_, NN_, NN_, NN_, nullptr, 0, nullptr);
  k_degpart<<<dim3(8, 16, C_), 256, 0, stream>>>(Hb, degp);
  k_dinv<<<dim3(16), 256, 0, stream>>>(Hb, degp, dinvb);
  k_colscale<<<dim3(NN_/256, C_), 256, 0, stream>>>(Hb, dinvb);
  k_combineT2<<<dim3(N_/32, N_/32), dim3(32,8), 0, stream>>>(A, filt + 2*C_*E_, HB2t);
  gemm_bt<1><<<dim3(16,16,C_), 256, 0, stream>>>(HB2t, Hb, H2t, N_, N_, NN_, NN_, NN_, nullptr, 0, nullptr);
  k_gcnprep<<<dim3(N_, C_), 256, 0, stream>>>(H2t, disv);
  k_pd<<<dim3(NN_/256, C_), 256, 0, stream>>>(H2t, disv, Pd);
  gemm_bt<1><<<dim3(N_/128, WOUT_/128, 1), 256, 0, stream>>>(Wt, Xbf, XWt, WIN_, N_, 0, 0, 0, nullptr, 0, nullptr);
  gemm_bt<2><<<dim3(WOUT_/128, N_/128, C_), 256, 0, stream>>>(Pd, XWt, catb, N_, C_*WOUT_, NN_, 0, WOUT_, disv, N_, gcnB);
  gemm_bt<3><<<dim3(WOUT_/128, N_/128, 1), 256, 0, stream>>>(catb, l1Wt, Xo, C_*WOUT_, WOUT_, 0, 0, 0, nullptr, 0, lin1B);
  k_zeropad<<<dim3((BTP_-BT_)*WOUT_/256), 256, 0, stream>>>(bs);
  k_pool<<<dim3(T_, B_), 256, 0, stream>>>(seqs, Xo, bs);
  gemm_bt<4><<<dim3((4*U_)/128, BTP_/128, 1), 256, 0, stream>>>(bs, Wihbf, Gxt, WOUT_, 0, 0, 0, 0, nullptr, 0, bsum);
  k_packWhh2<<<dim3(4096), 256, 0, stream>>>(Whh, WhhB);
  k_hinit<<<dim3(128), 256, 0, stream>>>(h0, Hglob);
  k_lstm_all<<<dim3(32), 256, 0, stream>>>(WhhB, Gxt, c0, seqlen, Hglob, syncv, act);
  k_score<<<dim3(N_/256, B_), 256, 0, stream>>>(act, sWt, (float*)d_out);
}

// Round 7
// 604.051 us; speedup vs baseline: 1.2565x; 1.2565x over previous
//
#include <hip/hip_runtime.h>
#include <stdint.h>

#define E_ 3
#define C_ 2
#define N_ 2048
#define B_ 64
#define T_ 50
#define WIN_ 256
#define WOUT_ 256
#define U_ 512
#define BT_ (B_*T_)
#define BTP_ 3328

typedef unsigned short u16;
typedef unsigned int u32;
typedef __bf16 bf16x8 __attribute__((ext_vector_type(8)));
typedef float f32x4 __attribute__((ext_vector_type(4)));

#define NN_ (2048LL*2048LL)

__device__ __forceinline__ float bf2f(u16 u){
  u32 x = ((u32)u) << 16; return __builtin_bit_cast(float, x);
}
__device__ __forceinline__ u16 f2bf(float f){
  u32 x = __builtin_bit_cast(u32, f);
  u32 r = (x + 0x7fffu + ((x >> 16) & 1u)) >> 16;
  return (u16)r;
}

__device__ __forceinline__ void gload16(const u16* g, u16* l){
  __builtin_amdgcn_global_load_lds((const __attribute__((address_space(1))) u32*)g,
                                   (__attribute__((address_space(3))) u32*)l, 16, 0, 0);
}

// ---------------- softmax filters: filt[(fi*C+c)*E+e] ----------------
__global__ void k_filters(const float* __restrict__ w1, const float* __restrict__ w2,
                          const float* __restrict__ w3, float* __restrict__ filt){
  const int t = threadIdx.x;
  if(t >= 3*C_) return;
  const int fi = t / C_, c = t % C_;
  const float* w = (fi==0) ? w1 : ((fi==1) ? w2 : w3);
  float v[E_]; float mx = -3.4e38f;
  for(int e=0;e<E_;e++){ v[e] = w[c*E_+e]; mx = fmaxf(mx, v[e]); }
  float s = 0.f;
  for(int e=0;e<E_;e++){ v[e] = expf(v[e]-mx); s += v[e]; }
  for(int e=0;e<E_;e++) filt[(fi*C_+c)*E_ + e] = v[e]/s;
}

// ---------------- fused combine: HA (direct) + HBt (transposed), A read ONCE ----------------
__global__ void k_combineAll(const float* __restrict__ A, const float* __restrict__ filt,
                             u16* __restrict__ HA, u16* __restrict__ HBt){
  __shared__ float te[3][32][33];
  const int ti = blockIdx.x, tj = blockIdx.y;
  const int x = threadIdx.x, y0 = threadIdx.y;
  #pragma unroll
  for(int i=0;i<4;i++){
    const int y = y0 + i*8;
    const long base = (long)(tj*32+y)*N_ + ti*32 + x;
    const float a0 = A[0*NN_+base], a1 = A[1*NN_+base], a2 = A[2*NN_+base];
    te[0][y][x]=a0; te[1][y][x]=a1; te[2][y][x]=a2;
    #pragma unroll
    for(int c=0;c<C_;c++)
      HA[c*NN_ + base] = f2bf(filt[c*E_]*a0 + filt[c*E_+1]*a1 + filt[c*E_+2]*a2);
  }
  __syncthreads();
  #pragma unroll
  for(int i=0;i<4;i++){
    const int y = y0 + i*8;
    const long ob = (long)(ti*32+y)*N_ + tj*32 + x;
    const float a0=te[0][x][y], a1=te[1][x][y], a2=te[2][x][y];
    #pragma unroll
    for(int c=0;c<C_;c++)
      HBt[c*NN_+ob] = f2bf(filt[(C_+c)*E_]*a0 + filt[(C_+c)*E_+1]*a1 + filt[(C_+c)*E_+2]*a2);
  }
}

// ---------------- HB2t both channels, one pass over A ----------------
__global__ void k_combineT2(const float* __restrict__ A, const float* __restrict__ f,
                            u16* __restrict__ outp){
  __shared__ float te[3][32][33];
  const int ti = blockIdx.x, tj = blockIdx.y;
  const int x = threadIdx.x, y0 = threadIdx.y;
  #pragma unroll
  for(int i=0;i<4;i++){
    const int y = y0 + i*8;
    const long base = (long)(tj*32+y)*N_ + ti*32 + x;
    te[0][y][x]=A[0*NN_+base]; te[1][y][x]=A[1*NN_+base]; te[2][y][x]=A[2*NN_+base];
  }
  __syncthreads();
  #pragma unroll
  for(int i=0;i<4;i++){
    const int y = y0 + i*8;
    const long ob = (long)(ti*32+y)*N_ + tj*32 + x;
    const float a0=te[0][x][y], a1=te[1][x][y], a2=te[2][x][y];
    #pragma unroll
    for(int c=0;c<C_;c++)
      outp[c*NN_+ob] = f2bf(f[c*E_]*a0 + f[c*E_+1]*a1 + f[c*E_+2]*a2);
  }
}

// ---------------- MFMA GEMM: OUT[i][j] = sum_k A[i][k]*B[j][k] ----------------
// MODE 1: bf16 raw; 2: bf16 relu(dis[row]*acc + bias[col]); 3: f32 acc + bias[col];
// MODE 4: Gq scatter: [(t*4+grp)*512+ug][b16][q] = acc + bias[col]
template<int MODE>
__global__ __launch_bounds__(256) void gemm_bt(
    const u16* __restrict__ Ag, const u16* __restrict__ Bg, void* __restrict__ Cg,
    int K, int ldc, long sA, long sB, long sC,
    const float* __restrict__ disv, int sDis, const float* __restrict__ bias)
{
  __shared__ u16 At[128*32];
  __shared__ u16 Bt[128*32];
  const int tid = threadIdx.x;
  const int w = tid >> 6, l = tid & 63;
  const int z = blockIdx.z;
  const u16* Ab = Ag + (long)z*sA;
  const u16* Bb = Bg + (long)z*sB;
  const int rowBase = blockIdx.y*128;
  const int colBase = blockIdx.x*128;

  f32x4 acc[4][4];
  #pragma unroll
  for(int i=0;i<4;i++)
    #pragma unroll
    for(int j=0;j<4;j++)
      acc[i][j] = f32x4{0.f,0.f,0.f,0.f};

  const int wr = w >> 1, wc = w & 1;
  const int arow0 = (w*2+0)*16 + (l>>2);
  const int arow1 = (w*2+1)*16 + (l>>2);
  const int kc = (((l&3) ^ ((l>>2)&3)))*8;
  const int frow = l & 15;
  const int fkc = l >> 4;

  const int nk = K >> 5;
  for(int kt=0; kt<nk; ++kt){
    const int k0 = kt << 5;
    gload16(Ab + (long)(rowBase+arow0)*K + k0 + kc, &At[(w*2+0)*512]);
    gload16(Ab + (long)(rowBase+arow1)*K + k0 + kc, &At[(w*2+1)*512]);
    gload16(Bb + (long)(colBase+arow0)*K + k0 + kc, &Bt[(w*2+0)*512]);
    gload16(Bb + (long)(colBase+arow1)*K + k0 + kc, &Bt[(w*2+1)*512]);
    __syncthreads();
    bf16x8 af[4], bfv[4];
    #pragma unroll
    for(int m=0;m<4;m++){
      const int rr = wr*64 + m*16 + frow;
      af[m] = *(const bf16x8*)&At[rr*32 + ((fkc ^ (rr&3))<<3)];
    }
    #pragma unroll
    for(int n=0;n<4;n++){
      const int rr = wc*64 + n*16 + frow;
      bfv[n] = *(const bf16x8*)&Bt[rr*32 + ((fkc ^ (rr&3))<<3)];
    }
    #pragma unroll
    for(int m=0;m<4;m++)
      #pragma unroll
      for(int n=0;n<4;n++)
        acc[m][n] = __builtin_amdgcn_mfma_f32_16x16x32_bf16(af[m], bfv[n], acc[m][n], 0, 0, 0);
    __syncthreads();
  }

  #pragma unroll
  for(int m=0;m<4;m++){
    const int row0 = rowBase + wr*64 + m*16 + (l>>4)*4;
    #pragma unroll
    for(int n=0;n<4;n++){
      const int col = colBase + wc*64 + n*16 + (l&15);
      #pragma unroll
      for(int r=0;r<4;r++){
        const float v = acc[m][n][r];
        if(MODE==1){
          ((u16*)Cg)[z*sC + (long)(row0+r)*ldc + col] = f2bf(v);
        } else if(MODE==2){
          float o = disv[z*(long)sDis + row0 + r]*v + bias[col];
          o = o > 0.f ? o : 0.f;
          ((u16*)Cg)[z*sC + (long)(row0+r)*ldc + col] = f2bf(o);
        } else if(MODE==3){
          ((float*)Cg)[z*sC + (long)(row0+r)*ldc + col] = v + bias[col];
        } else if(MODE==4){
          const int row = row0 + r;
          if(row < BT_){
            const int bb = row/50, tt = row - bb*50;
            const int gq = col >> 9, ugg = col & 511;
            ((float*)Cg)[((((long)tt*4 + (bb>>4))*512 + ugg)*16 + (bb&15))*4 + gq] = v + bias[col];
          }
        }
      }
    }
  }
}

// ---------------- column-degree partial sums ----------------
__global__ void k_degpart(const u16* __restrict__ H, float* __restrict__ partial){
  const int c = blockIdx.z;
  const int col = blockIdx.x*256 + threadIdx.x;
  const int r0 = blockIdx.y*128;
  const u16* Hc = H + c*NN_;
  float s = 0.f;
  #pragma unroll 4
  for(int r=0;r<128;r++) s += bf2f(Hc[(long)(r0+r)*N_ + col]);
  partial[((long)c*16 + blockIdx.y)*N_ + col] = s;
}

// ---------------- dinv[c][m] = 1/(colsum - diag), guarded ----------------
__global__ void k_dinv(const u16* __restrict__ H, const float* __restrict__ partial,
                       float* __restrict__ dinvb){
  const int i = blockIdx.x*256 + threadIdx.x;
  const int c = i >> 11, m = i & (N_-1);
  float s = 0.f;
  #pragma unroll
  for(int p=0;p<16;p++) s += partial[((long)c*16 + p)*N_ + m];
  s -= bf2f(H[c*NN_ + (long)m*N_ + m]);
  dinvb[i] = s > 0.f ? 1.f/s : 0.f;
}

// ---------------- H[j][i] = (j==i) ? 0 : H*dinv[i] ----------------
__global__ void k_colscale(u16* __restrict__ H, const float* __restrict__ dinvb){
  const long i = (long)blockIdx.x*256 + threadIdx.x;
  const int c = blockIdx.y;
  const int j = (int)(i >> 11), ii = (int)(i & (N_-1));
  const long idx = c*NN_ + i;
  const float v = (j==ii) ? 0.f : bf2f(H[idx])*dinvb[c*N_ + ii];
  H[idx] = f2bf(v);
}

// ---------------- dis[c][j] = rsqrt(1 + rowsum(H2t[c][j][:])) ----------------
__global__ void k_gcnprep(const u16* __restrict__ H2t, float* __restrict__ disv){
  const int c = blockIdx.y, j = blockIdx.x;
  const u16* r = H2t + (c*(long)N_ + j)*N_;
  float s = 0.f;
  for(int i=threadIdx.x;i<N_;i+=256) s += bf2f(r[i]);
  __shared__ float red[256];
  red[threadIdx.x] = s;
  __syncthreads();
  for(int st=128; st>0; st>>=1){
    if(threadIdx.x < st) red[threadIdx.x] += red[threadIdx.x+st];
    __syncthreads();
  }
  if(threadIdx.x==0){
    const float deg = red[0] + 1.f;
    disv[c*N_ + j] = deg > 0.f ? rsqrtf(deg) : 0.f;
  }
}

// ---------------- Pd[c][j][i] = (H2t + I) * dis[i] ----------------
__global__ void k_pd(const u16* __restrict__ H2t, const float* __restrict__ disv,
                     u16* __restrict__ Pd){
  const long i = (long)blockIdx.x*256 + threadIdx.x;
  const int c = blockIdx.y;
  const int j = (int)(i >> 11);
  const int ii = (int)(i & (N_-1));
  const long idx = c*NN_ + i;
  const float v = bf2f(H2t[idx]) + (ii==j ? 1.f : 0.f);
  Pd[idx] = f2bf(v*disv[c*N_ + ii]);
}

// ---------------- transpose f32 in[R][Cc] -> bf16 out[Cc][R] ----------------
__global__ void k_transpose(const float* __restrict__ in, u16* __restrict__ out,
                            int R, int Cc){
  __shared__ float tt[32][33];
  const int ti = blockIdx.x, tj = blockIdx.y;
  const int x = threadIdx.x, y0 = threadIdx.y;
  #pragma unroll
  for(int i=0;i<4;i++){
    const int y = y0 + i*8;
    tt[y][x] = in[(long)(tj*32+y)*Cc + ti*32 + x];
  }
  __syncthreads();
  #pragma unroll
  for(int i=0;i<4;i++){
    const int y = y0 + i*8;
    out[(long)(ti*32+y)*R + tj*32 + x] = f2bf(tt[x][y]);
  }
}

// ---------------- cast f32 -> bf16 ----------------
__global__ void k_cast(const float* __restrict__ in, u16* __restrict__ out){
  const long i = (long)blockIdx.x*256 + threadIdx.x;
  out[i] = f2bf(in[i]);
}

// ---------------- bsum = bih + bhh; zero barrier flags ----------------
__global__ void k_bias(const float* __restrict__ bih, const float* __restrict__ bhh,
                       float* __restrict__ bsum, u32* __restrict__ flagv){
  const int i = blockIdx.x*256 + threadIdx.x;
  bsum[i] = bih[i] + bhh[i];
  flagv[i] = 0;   // 2048 u32 = full flag area
}

// ---------------- basket max-pool via active list ----------------
__global__ void k_pool(const float* __restrict__ seqs, const float* __restrict__ X_,
                       u16* __restrict__ bs){
  const int t = blockIdx.x, b = blockIdx.y;
  const float* mask = seqs + ((long)b*T_ + t)*N_;
  const int f = threadIdx.x;
  __shared__ int list[N_];
  __shared__ int cnt;
  if(f==0) cnt = 0;
  __syncthreads();
  for(int n0=f; n0<N_; n0+=256){
    if(mask[n0] > 0.f){
      int p = atomicAdd(&cnt, 1);
      list[p] = n0;
    }
  }
  __syncthreads();
  const int m = cnt;
  float mx = -3.4e38f;
  for(int i=0;i<m;i++)
    mx = fmaxf(mx, X_[(long)list[i]*WOUT_ + f]);
  bs[((long)b*T_ + t)*WOUT_ + f] = f2bf(m>0 ? mx : 0.f);
}

__global__ void k_zeropad(u16* __restrict__ bs){
  const int i = blockIdx.x*256 + threadIdx.x;
  bs[(long)BT_*WOUT_ + i] = 0;
}

// ---------------- pack Whh for register-resident A-frags ----------------
// P[(((s*8+w)*64+l)*16+kk)*8+e] = Whh[grow][k]; lr=w*16+(l&15); gam=lr&3; ui=lr>>2;
// grow=gam*512+s*32+ui; k=kk*32+(l>>4)*8+e
__global__ void k_packWhh3(const float* __restrict__ Whh, u16* __restrict__ P){
  const long idx = (long)blockIdx.x*256 + threadIdx.x;  // 0..1048575
  const int e  = (int)(idx & 7);
  const int kk = (int)((idx >> 3) & 15);
  const int l  = (int)((idx >> 7) & 63);
  const int w  = (int)((idx >> 13) & 7);
  const int s  = (int)(idx >> 16);
  const int lr = w*16 + (l & 15);
  const int gam = lr & 3, ui = lr >> 2;
  const int grow = gam*512 + s*32 + ui;
  const int k = kk*32 + (l >> 4)*8 + e;
  P[idx] = f2bf(Whh[(long)grow*512 + k]);
}

// ---------------- Hglob init: per-group [16 b][512 u] pre-swizzled ----------------
__global__ void k_hinit(const float* __restrict__ h0, u16* __restrict__ Hglob){
  const int idx = blockIdx.x*256 + threadIdx.x;  // 0..32767
  const int b = idx >> 9, u = idx & 511;
  const int grp = b >> 4, bl = b & 15;
  Hglob[grp*16384 + (bl << 9) + (u ^ ((bl & 7) << 3))] = f2bf(h0[idx]);
}

// ---------------- persistent LSTM v3: 4 indep batch-groups x 16 blocks, W in VGPRs ----------------
__global__ __launch_bounds__(512) void k_lstm_all(
    const u16* __restrict__ WhhP, const float* __restrict__ Gq,
    const float* __restrict__ c0v, const int* __restrict__ seqlen,
    u16* __restrict__ Hglob, u32* __restrict__ flagv, float* __restrict__ act)
{
  __shared__ u16 Hl[16*512];
  const int tid = threadIdx.x;
  const int w = tid >> 6, l = tid & 63;
  const int grp = blockIdx.x >> 4, s = blockIdx.x & 15;
  const int fr = l & 15, hi = l >> 4;

  // Whh A-frags -> registers (held across all steps)
  bf16x8 wreg[16];
  const u16* wp = WhhP + (((long)s*8 + w)*64 + l)*128;
  #pragma unroll
  for(int kk=0; kk<16; ++kk)
    wreg[kk] = *(const bf16x8*)&wp[kk*8];

  const int ui = w*4 + hi;              // 0..31
  const int ug = s*32 + ui;             // 0..511
  const int bl = fr;                    // batch within group
  const int bg = grp*16 + bl;
  float cst = c0v[bg*U_ + ug];
  const int sl = seqlen[bg] - 1;
  u16* Hbase = Hglob + grp*16384;
  const int hswz = (bl & 7) << 3;
  const int fi = (grp*16 + fr)*32;      // own-poll flag index (lanes 0..15 distinct)

  for(int t=0; t<T_; ++t){
    // Gq prefetch: ONE dwordx4 per thread, overlapped with H stage drain
    const float4 gq = *(const float4*)&Gq[((((long)t*4 + grp)*512 + ug)*16 + bl)*4];
    // stage H_t (16 KB): 2 rounds x 8 waves x 1 KB
    const u16* Hin = Hbase + (t & 1)*8192;
    #pragma unroll
    for(int r=0; r<2; ++r)
      gload16(Hin + (r*8 + w)*512 + l*8, &Hl[(r*8 + w)*512]);
    __syncthreads();

    // gates: 16 MFMA, W in regs, H from LDS
    f32x4 acc = f32x4{0.f,0.f,0.f,0.f};
    #pragma unroll
    for(int kk=0; kk<16; ++kk){
      const int ke = kk*32 + hi*8;
      bf16x8 bb = *(const bf16x8*)&Hl[(bl << 9) + (ke ^ hswz)];
      acc = __builtin_amdgcn_mfma_f32_16x16x32_bf16(wreg[kk], bb, acc, 0, 0, 0);
    }

    // epilogue: thread owns (batch bl, unit ug), gates i,f,g,o = acc + gq
    const float a0 = acc[0] + gq.x;
    const float a1 = acc[1] + gq.y;
    const float a2 = acc[2] + gq.z;
    const float a3 = acc[3] + gq.w;
    const float ig = 1.f/(1.f + expf(-a0));
    const float fg = 1.f/(1.f + expf(-a1));
    const float gg = tanhf(a2);
    const float og = 1.f/(1.f + expf(-a3));
    cst = fg*cst + ig*gg;
    const float h = og*tanhf(cst);
    u16* Hout = Hbase + ((t+1) & 1)*8192;
    Hout[(bl << 9) + (ug ^ hswz)] = f2bf(h);
    if(sl == t) act[bg*U_ + ug] = h;

    if(t == T_-1) break;
    __syncthreads();                    // drain all waves' h stores (vmcnt 0)
    if(tid == 0)
      __hip_atomic_store(&flagv[(grp*16 + s)*32], (u32)(t+1),
                         __ATOMIC_RELEASE, __HIP_MEMORY_SCOPE_AGENT);
    if(w == 0){                         // lanes 0..15 poll 16 distinct cachelines
      while(__hip_atomic_load(&flagv[fi], __ATOMIC_ACQUIRE,
                              __HIP_MEMORY_SCOPE_AGENT) <= (u32)t){
        __builtin_amdgcn_s_sleep(1);
      }
    }
    __syncthreads();
  }
}

// ---------------- out[b][n] = sigmoid(actual[b] . sWt[:,n])  (f32 out) ----------------
__global__ void k_score(const float* __restrict__ actual, const u16* __restrict__ sWt,
                        float* __restrict__ out){
  const int n = blockIdx.x*256 + threadIdx.x;
  const int b = blockIdx.y;
  const float* ab = actual + (long)b*U_;
  float s = 0.f;
  for(int uu=0; uu<U_; uu++) s += ab[uu]*bf2f(sWt[(long)uu*N_ + n]);
  out[(long)b*N_ + n] = 1.f/(1.f + expf(-s));
}

extern "C" void kernel_launch(void* const* d_in, const int* in_sizes, int n_in,
                              void* d_out, int out_size, void* d_ws, size_t ws_size,
                              hipStream_t stream){
  (void)in_sizes; (void)n_in; (void)out_size; (void)ws_size;
  const float* A      = (const float*)d_in[0];
  const float* X      = (const float*)d_in[1];
  const float* seqs   = (const float*)d_in[2];
  const int*   seqlen = (const int*)d_in[3];
  const float* h0     = (const float*)d_in[4];
  const float* c0     = (const float*)d_in[5];
  const float* gtw1   = (const float*)d_in[6];
  const float* gtw2   = (const float*)d_in[7];
  const float* gtw3   = (const float*)d_in[8];
  const float* gcnW   = (const float*)d_in[9];
  const float* gcnB   = (const float*)d_in[10];
  const float* lin1W  = (const float*)d_in[11];
  const float* lin1B  = (const float*)d_in[12];
  const float* Wih    = (const float*)d_in[13];
  const float* Whh    = (const float*)d_in[14];
  const float* bihp   = (const float*)d_in[15];
  const float* bhhp   = (const float*)d_in[16];
  const float* scoreW = (const float*)d_in[17];

  char* ws = (char*)d_ws;
  u16* buf0 = (u16*)(ws + 0);
  u16* buf1 = (u16*)(ws + 16777216);
  u16* buf2 = (u16*)(ws + 33554432);
  char* S0  = ws + 50331648;
  float* filt  = (float*)(S0 + 0);
  float* disv  = (float*)(S0 + 1024);
  u16*  Wt     = (u16*) (S0 + 17408);
  u16*  XWt    = (u16*) (S0 + 148480);
  u16*  catb   = (u16*) (S0 + 1197056);
  u16*  l1Wt   = (u16*) (S0 + 3294208);
  float* Xo    = (float*)(S0 + 3556352);
  u16*  bs     = (u16*) (S0 + 5653504);
  float* act   = (float*)(S0 + 7357440);
  u16*  sWt    = (u16*) (S0 + 7488512);
  u16*  WhhB   = (u16*) (S0 + 9585664);
  u16*  Xbf    = (u16*) (S0 + 11682816);
  u16*  Wihbf  = (u16*) (S0 + 12731392);
  float* bsum  = (float*)(S0 + 13779968);
  u16*  Hglob  = (u16*) (S0 + 13788160);   // 4 groups x 16384 elems x 2B = 128 KB
  u32*  flagv  = (u32*) (S0 + 13919232);   // 2048 u32 (64 flags, 128B apart)
  float* degp  = (float*)(S0 + 14050304);
  float* dinvb = (float*)(S0 + 14312448);
  u16* HA   = buf0;
  u16* HBt  = buf1;
  u16* Hb   = buf2;
  u16* HB2t = buf0;
  u16* H2t  = buf1;
  u16* Pd   = buf1;
  float* Gq = (float*)ws;   // 26.2 MiB over buf0+buf1 (dead by then)

  k_filters<<<1, 64, 0, stream>>>(gtw1, gtw2, gtw3, filt);
  k_combineAll<<<dim3(N_/32, N_/32), dim3(32,8), 0, stream>>>(A, filt, HA, HBt);
  k_transpose<<<dim3(WOUT_/32, WIN_/32), dim3(32,8), 0, stream>>>(gcnW, Wt, WIN_, WOUT_);
  k_transpose<<<dim3(WOUT_/32, (C_*WOUT_)/32), dim3(32,8), 0, stream>>>(lin1W, l1Wt, C_*WOUT_, WOUT_);
  k_transpose<<<dim3(U_/32, N_/32), dim3(32,8), 0, stream>>>(scoreW, sWt, N_, U_);
  k_cast<<<dim3((N_*WIN_)/256), 256, 0, stream>>>(X, Xbf);
  k_cast<<<dim3((4*U_*WOUT_)/256), 256, 0, stream>>>(Wih, Wihbf);
  k_bias<<<dim3((4*U_)/256), 256, 0, stream>>>(bihp, bhhp, bsum, flagv);
  gemm_bt<1><<<dim3(16,16,C_), 256, 0, stream>>>(HA, HBt, Hb, N_, N_, NN_, NN_, NN_, nullptr, 0, nullptr);
  k_degpart<<<dim3(8, 16, C_), 256, 0, stream>>>(Hb, degp);
  k_dinv<<<dim3(16), 256, 0, stream>>>(Hb, degp, dinvb);
  k_colscale<<<dim3(NN_/256, C_), 256, 0, stream>>>(Hb, dinvb);
  k_combineT2<<<dim3(N_/32, N_/32), dim3(32,8), 0, stream>>>(A, filt + 2*C_*E_, HB2t);
  gemm_bt<1><<<dim3(16,16,C_), 256, 0, stream>>>(HB2t, Hb, H2t, N_, N_, NN_, NN_, NN_, nullptr, 0, nullptr);
  k_gcnprep<<<dim3(N_, C_), 256, 0, stream>>>(H2t, disv);
  k_pd<<<dim3(NN_/256, C_), 256, 0, stream>>>(H2t, disv, Pd);
  gemm_bt<1><<<dim3(N_/128, WOUT_/128, 1), 256, 0, stream>>>(Wt, Xbf, XWt, WIN_, N_, 0, 0, 0, nullptr, 0, nullptr);
  gemm_bt<2><<<dim3(WOUT_/128, N_/128, C_), 256, 0, stream>>>(Pd, XWt, catb, N_, C_*WOUT_, NN_, 0, WOUT_, disv, N_, gcnB);
  gemm_bt<3><<<dim3(WOUT_/128, N_/128, 1), 256, 0, stream>>>(catb, l1Wt, Xo, C_*WOUT_, WOUT_, 0, 0, 0, nullptr, 0, lin1B);
  k_zeropad<<<dim3((BTP_-BT_)*WOUT_/256), 256, 0, stream>>>(bs);
  k_pool<<<dim3(T_, B_), 256, 0, stream>>>(seqs, Xo, bs);
  gemm_bt<4><<<dim3((4*U_)/128, BTP_/128, 1), 256, 0, stream>>>(bs, Wihbf, Gq, WOUT_, 0, 0, 0, 0, nullptr, 0, bsum);
  k_packWhh3<<<dim3(4096), 256, 0, stream>>>(Whh, WhhB);
  k_hinit<<<dim3(128), 256, 0, stream>>>(h0, Hglob);
  k_lstm_all<<<dim3(64), 512, 0, stream>>>(WhhB, Gq, c0, seqlen, Hglob, flagv, act);
  k_score<<<dim3(N_/256, B_), 256, 0, stream>>>(act, sWt, (float*)d_out);
}

// Round 8
// 576.494 us; speedup vs baseline: 1.3165x; 1.0478x over previous
//
#include <hip/hip_runtime.h>
#include <stdint.h>

#define E_ 3
#define C_ 2
#define N_ 2048
#define B_ 64
#define T_ 50
#define WIN_ 256
#define WOUT_ 256
#define U_ 512
#define BT_ (B_*T_)
#define BTP_ 3328

typedef unsigned short u16;
typedef unsigned int u32;
typedef __bf16 bf16x8 __attribute__((ext_vector_type(8)));
typedef float f32x4 __attribute__((ext_vector_type(4)));

#define NN_ (2048LL*2048LL)

__device__ __forceinline__ float bf2f(u16 u){
  u32 x = ((u32)u) << 16; return __builtin_bit_cast(float, x);
}
__device__ __forceinline__ u16 f2bf(float f){
  u32 x = __builtin_bit_cast(u32, f);
  u32 r = (x + 0x7fffu + ((x >> 16) & 1u)) >> 16;
  return (u16)r;
}

__device__ __forceinline__ void gload16(const u16* g, u16* l){
  __builtin_amdgcn_global_load_lds((const __attribute__((address_space(1))) u32*)g,
                                   (__attribute__((address_space(3))) u32*)l, 16, 0, 0);
}

// ---------------- prep0: softmax filters + bsum + flag zero ----------------
__global__ void k_prep0(const float* __restrict__ w1, const float* __restrict__ w2,
                        const float* __restrict__ w3, float* __restrict__ filt,
                        const float* __restrict__ bih, const float* __restrict__ bhh,
                        float* __restrict__ bsum, u32* __restrict__ flagv){
  const int i = blockIdx.x*256 + threadIdx.x;
  bsum[i] = bih[i] + bhh[i];
  flagv[i] = 0;
  if(blockIdx.x==0 && threadIdx.x < 3*C_){
    const int t = threadIdx.x;
    const int fi = t / C_, c = t % C_;
    const float* w = (fi==0) ? w1 : ((fi==1) ? w2 : w3);
    float v[E_]; float mx = -3.4e38f;
    for(int e=0;e<E_;e++){ v[e] = w[c*E_+e]; mx = fmaxf(mx, v[e]); }
    float s = 0.f;
    for(int e=0;e<E_;e++){ v[e] = expf(v[e]-mx); s += v[e]; }
    for(int e=0;e<E_;e++) filt[(fi*C_+c)*E_ + e] = v[e]/s;
  }
}

// ---------------- fused combine: HA (direct) + HBt (transposed), A read ONCE ----------------
__global__ void k_combineAll(const float* __restrict__ A, const float* __restrict__ filt,
                             u16* __restrict__ HA, u16* __restrict__ HBt){
  __shared__ float te[3][32][33];
  const int ti = blockIdx.x, tj = blockIdx.y;
  const int x = threadIdx.x, y0 = threadIdx.y;
  #pragma unroll
  for(int i=0;i<4;i++){
    const int y = y0 + i*8;
    const long base = (long)(tj*32+y)*N_ + ti*32 + x;
    const float a0 = A[0*NN_+base], a1 = A[1*NN_+base], a2 = A[2*NN_+base];
    te[0][y][x]=a0; te[1][y][x]=a1; te[2][y][x]=a2;
    #pragma unroll
    for(int c=0;c<C_;c++)
      HA[c*NN_ + base] = f2bf(filt[c*E_]*a0 + filt[c*E_+1]*a1 + filt[c*E_+2]*a2);
  }
  __syncthreads();
  #pragma unroll
  for(int i=0;i<4;i++){
    const int y = y0 + i*8;
    const long ob = (long)(ti*32+y)*N_ + tj*32 + x;
    const float a0=te[0][x][y], a1=te[1][x][y], a2=te[2][x][y];
    #pragma unroll
    for(int c=0;c<C_;c++)
      HBt[c*NN_+ob] = f2bf(filt[(C_+c)*E_]*a0 + filt[(C_+c)*E_+1]*a1 + filt[(C_+c)*E_+2]*a2);
  }
}

// ---------------- HB2t both channels, one pass over A ----------------
__global__ void k_combineT2(const float* __restrict__ A, const float* __restrict__ f,
                            u16* __restrict__ outp){
  __shared__ float te[3][32][33];
  const int ti = blockIdx.x, tj = blockIdx.y;
  const int x = threadIdx.x, y0 = threadIdx.y;
  #pragma unroll
  for(int i=0;i<4;i++){
    const int y = y0 + i*8;
    const long base = (long)(tj*32+y)*N_ + ti*32 + x;
    te[0][y][x]=A[0*NN_+base]; te[1][y][x]=A[1*NN_+base]; te[2][y][x]=A[2*NN_+base];
  }
  __syncthreads();
  #pragma unroll
  for(int i=0;i<4;i++){
    const int y = y0 + i*8;
    const long ob = (long)(ti*32+y)*N_ + tj*32 + x;
    const float a0=te[0][x][y], a1=te[1][x][y], a2=te[2][x][y];
    #pragma unroll
    for(int c=0;c<C_;c++)
      outp[c*NN_+ob] = f2bf(f[c*E_]*a0 + f[c*E_+1]*a1 + f[c*E_+2]*a2);
  }
}

// ---------------- MFMA GEMM: OUT[i][j] = sum_k A[i][k]*B[j][k] ----------------
template<int MODE>
__global__ __launch_bounds__(256) void gemm_bt(
    const u16* __restrict__ Ag, const u16* __restrict__ Bg, void* __restrict__ Cg,
    int K, int ldc, long sA, long sB, long sC,
    const float* __restrict__ disv, int sDis, const float* __restrict__ bias)
{
  __shared__ u16 At[128*32];
  __shared__ u16 Bt[128*32];
  const int tid = threadIdx.x;
  const int w = tid >> 6, l = tid & 63;
  const int z = blockIdx.z;
  const u16* Ab = Ag + (long)z*sA;
  const u16* Bb = Bg + (long)z*sB;
  const int rowBase = blockIdx.y*128;
  const int colBase = blockIdx.x*128;

  f32x4 acc[4][4];
  #pragma unroll
  for(int i=0;i<4;i++)
    #pragma unroll
    for(int j=0;j<4;j++)
      acc[i][j] = f32x4{0.f,0.f,0.f,0.f};

  const int wr = w >> 1, wc = w & 1;
  const int arow0 = (w*2+0)*16 + (l>>2);
  const int arow1 = (w*2+1)*16 + (l>>2);
  const int kc = (((l&3) ^ ((l>>2)&3)))*8;
  const int frow = l & 15;
  const int fkc = l >> 4;

  const int nk = K >> 5;
  for(int kt=0; kt<nk; ++kt){
    const int k0 = kt << 5;
    gload16(Ab + (long)(rowBase+arow0)*K + k0 + kc, &At[(w*2+0)*512]);
    gload16(Ab + (long)(rowBase+arow1)*K + k0 + kc, &At[(w*2+1)*512]);
    gload16(Bb + (long)(colBase+arow0)*K + k0 + kc, &Bt[(w*2+0)*512]);
    gload16(Bb + (long)(colBase+arow1)*K + k0 + kc, &Bt[(w*2+1)*512]);
    __syncthreads();
    bf16x8 af[4], bfv[4];
    #pragma unroll
    for(int m=0;m<4;m++){
      const int rr = wr*64 + m*16 + frow;
      af[m] = *(const bf16x8*)&At[rr*32 + ((fkc ^ (rr&3))<<3)];
    }
    #pragma unroll
    for(int n=0;n<4;n++){
      const int rr = wc*64 + n*16 + frow;
      bfv[n] = *(const bf16x8*)&Bt[rr*32 + ((fkc ^ (rr&3))<<3)];
    }
    #pragma unroll
    for(int m=0;m<4;m++)
      #pragma unroll
      for(int n=0;n<4;n++)
        acc[m][n] = __builtin_amdgcn_mfma_f32_16x16x32_bf16(af[m], bfv[n], acc[m][n], 0, 0, 0);
    __syncthreads();
  }

  #pragma unroll
  for(int m=0;m<4;m++){
    const int row0 = rowBase + wr*64 + m*16 + (l>>4)*4;
    #pragma unroll
    for(int n=0;n<4;n++){
      const int col = colBase + wc*64 + n*16 + (l&15);
      #pragma unroll
      for(int r=0;r<4;r++){
        const float v = acc[m][n][r];
        if(MODE==1){
          ((u16*)Cg)[z*sC + (long)(row0+r)*ldc + col] = f2bf(v);
        } else if(MODE==2){
          float o = disv[z*(long)sDis + row0 + r]*v + bias[col];
          o = o > 0.f ? o : 0.f;
          ((u16*)Cg)[z*sC + (long)(row0+r)*ldc + col] = f2bf(o);
        } else if(MODE==3){
          ((float*)Cg)[z*sC + (long)(row0+r)*ldc + col] = v + bias[col];
        } else if(MODE==4){
          const int row = row0 + r;
          if(row < BT_){
            const int bb = row/50, tt = row - bb*50;
            const int gq = col >> 9, ugg = col & 511;
            ((float*)Cg)[((((long)tt*4 + (bb>>4))*512 + ugg)*16 + (bb&15))*4 + gq] = v + bias[col];
          }
        }
      }
    }
  }
}

// ---------------- column-degree partial sums ----------------
__global__ void k_degpart(const u16* __restrict__ H, float* __restrict__ partial){
  const int c = blockIdx.z;
  const int col = blockIdx.x*256 + threadIdx.x;
  const int r0 = blockIdx.y*128;
  const u16* Hc = H + c*NN_;
  float s = 0.f;
  #pragma unroll 4
  for(int r=0;r<128;r++) s += bf2f(Hc[(long)(r0+r)*N_ + col]);
  partial[((long)c*16 + blockIdx.y)*N_ + col] = s;
}

// ---------------- dinv[c][m] = 1/(colsum - diag), guarded ----------------
__global__ void k_dinv(const u16* __restrict__ H, const float* __restrict__ partial,
                       float* __restrict__ dinvb){
  const int i = blockIdx.x*256 + threadIdx.x;
  const int c = i >> 11, m = i & (N_-1);
  float s = 0.f;
  #pragma unroll
  for(int p=0;p<16;p++) s += partial[((long)c*16 + p)*N_ + m];
  s -= bf2f(H[c*NN_ + (long)m*N_ + m]);
  dinvb[i] = s > 0.f ? 1.f/s : 0.f;
}

// ---------------- H[j][i] = (j==i) ? 0 : H*dinv[i] ----------------
__global__ void k_colscale(u16* __restrict__ H, const float* __restrict__ dinvb){
  const long i = (long)blockIdx.x*256 + threadIdx.x;
  const int c = blockIdx.y;
  const int j = (int)(i >> 11), ii = (int)(i & (N_-1));
  const long idx = c*NN_ + i;
  const float v = (j==ii) ? 0.f : bf2f(H[idx])*dinvb[c*N_ + ii];
  H[idx] = f2bf(v);
}

// ---------------- dis[c][j] = rsqrt(1 + rowsum(H2t[c][j][:])) ----------------
__global__ void k_gcnprep(const u16* __restrict__ H2t, float* __restrict__ disv){
  const int c = blockIdx.y, j = blockIdx.x;
  const u16* r = H2t + (c*(long)N_ + j)*N_;
  float s = 0.f;
  for(int i=threadIdx.x;i<N_;i+=256) s += bf2f(r[i]);
  __shared__ float red[256];
  red[threadIdx.x] = s;
  __syncthreads();
  for(int st=128; st>0; st>>=1){
    if(threadIdx.x < st) red[threadIdx.x] += red[threadIdx.x+st];
    __syncthreads();
  }
  if(threadIdx.x==0){
    const float deg = red[0] + 1.f;
    disv[c*N_ + j] = deg > 0.f ? rsqrtf(deg) : 0.f;
  }
}

// ---------------- Pd[c][j][i] = (H2t + I) * dis[i] ----------------
__global__ void k_pd(const u16* __restrict__ H2t, const float* __restrict__ disv,
                     u16* __restrict__ Pd){
  const long i = (long)blockIdx.x*256 + threadIdx.x;
  const int c = blockIdx.y;
  const int j = (int)(i >> 11);
  const int ii = (int)(i & (N_-1));
  const long idx = c*NN_ + i;
  const float v = bf2f(H2t[idx]) + (ii==j ? 1.f : 0.f);
  Pd[idx] = f2bf(v*disv[c*N_ + ii]);
}

// ---------------- 3-in-1 transpose f32 -> bf16 ----------------
__global__ void k_transpose3(const float* __restrict__ gcnW, u16* __restrict__ Wt,
                             const float* __restrict__ lin1W, u16* __restrict__ l1Wt,
                             const float* __restrict__ scoreW, u16* __restrict__ sWt){
  const float* in; u16* out; int R, Cc;
  if(blockIdx.z==0){ in=gcnW;  out=Wt;   R=WIN_;     Cc=WOUT_; }
  else if(blockIdx.z==1){ in=lin1W; out=l1Wt; R=C_*WOUT_; Cc=WOUT_; }
  else { in=scoreW; out=sWt; R=N_; Cc=U_; }
  const int ti = blockIdx.x, tj = blockIdx.y;
  if(ti >= (Cc>>5) || tj >= (R>>5)) return;
  __shared__ float tt[32][33];
  const int x = threadIdx.x, y0 = threadIdx.y;
  #pragma unroll
  for(int i=0;i<4;i++){
    const int y = y0 + i*8;
    tt[y][x] = in[(long)(tj*32+y)*Cc + ti*32 + x];
  }
  __syncthreads();
  #pragma unroll
  for(int i=0;i<4;i++){
    const int y = y0 + i*8;
    out[(long)(ti*32+y)*R + tj*32 + x] = f2bf(tt[x][y]);
  }
}

// ---------------- dual cast f32 -> bf16 (X then Wih) ----------------
__global__ void k_cast2(const float* __restrict__ X, u16* __restrict__ Xbf,
                        const float* __restrict__ Wih, u16* __restrict__ Wihbf){
  const long i = (long)blockIdx.x*256 + threadIdx.x;
  if(i < (long)N_*WIN_) Xbf[i] = f2bf(X[i]);
  else { const long j = i - (long)N_*WIN_; Wihbf[j] = f2bf(Wih[j]); }
}

// ---------------- basket max-pool (grid 52x64; t>=50 writes pad zeros) ----------------
__global__ void k_pool(const float* __restrict__ seqs, const float* __restrict__ X_,
                       u16* __restrict__ bs){
  const int t = blockIdx.x, b = blockIdx.y;
  const int f = threadIdx.x;
  if(t >= T_){
    bs[(long)(BT_ + b*2 + (t-T_))*WOUT_ + f] = 0;
    return;
  }
  const float* mask = seqs + ((long)b*T_ + t)*N_;
  __shared__ int list[N_];
  __shared__ int cnt;
  if(f==0) cnt = 0;
  __syncthreads();
  for(int n0=f; n0<N_; n0+=256){
    if(mask[n0] > 0.f){
      int p = atomicAdd(&cnt, 1);
      list[p] = n0;
    }
  }
  __syncthreads();
  const int m = cnt;
  float mx = -3.4e38f;
  for(int i=0;i<m;i++)
    mx = fmaxf(mx, X_[(long)list[i]*WOUT_ + f]);
  bs[((long)b*T_ + t)*WOUT_ + f] = f2bf(m>0 ? mx : 0.f);
}

// ---------------- pack Whh for register-resident A-frags ----------------
__global__ void k_packWhh3(const float* __restrict__ Whh, u16* __restrict__ P){
  const long idx = (long)blockIdx.x*256 + threadIdx.x;
  const int e  = (int)(idx & 7);
  const int kk = (int)((idx >> 3) & 15);
  const int l  = (int)((idx >> 7) & 63);
  const int w  = (int)((idx >> 13) & 7);
  const int s  = (int)(idx >> 16);
  const int lr = w*16 + (l & 15);
  const int gam = lr & 3, ui = lr >> 2;
  const int grow = gam*512 + s*32 + ui;
  const int k = kk*32 + (l >> 4)*8 + e;
  P[idx] = f2bf(Whh[(long)grow*512 + k]);
}

// ---------------- Hglob init ----------------
__global__ void k_hinit(const float* __restrict__ h0, u16* __restrict__ Hglob){
  const int idx = blockIdx.x*256 + threadIdx.x;
  const int b = idx >> 9, u = idx & 511;
  const int grp = b >> 4, bl = b & 15;
  Hglob[grp*16384 + (bl << 9) + (u ^ ((bl & 7) << 3))] = f2bf(h0[idx]);
}

// ---------------- persistent LSTM v4: XCD-affine groups + gq prefetch ----------------
__global__ __launch_bounds__(512) void k_lstm_all(
    const u16* __restrict__ WhhP, const float* __restrict__ Gq,
    const float* __restrict__ c0v, const int* __restrict__ seqlen,
    u16* __restrict__ Hglob, u32* __restrict__ flagv, float* __restrict__ act)
{
  __shared__ u16 Hl[16*512];
  const int tid = threadIdx.x;
  const int w = tid >> 6, l = tid & 63;
  // XCD-affinity: group g = blockIdx&3 -> blocks {g, g+4, ...} land on ~2 XCDs (heuristic)
  const int grp = blockIdx.x & 3, s = blockIdx.x >> 2;
  const int fr = l & 15, hi = l >> 4;

  bf16x8 wreg[16];
  const u16* wp = WhhP + (((long)s*8 + w)*64 + l)*128;
  #pragma unroll
  for(int kk=0; kk<16; ++kk)
    wreg[kk] = *(const bf16x8*)&wp[kk*8];

  const int ui = w*4 + hi;
  const int ug = s*32 + ui;
  const int bl = fr;
  const int bg = grp*16 + bl;
  float cst = c0v[bg*U_ + ug];
  const int sl = seqlen[bg] - 1;
  u16* Hbase = Hglob + grp*16384;
  const int hswz = (bl & 7) << 3;
  const int fi = (grp*16 + fr)*32;
  const long gqbase = (((long)grp*512 + ug)*16 + bl)*4;

  float4 gq_nxt = *(const float4*)&Gq[gqbase];   // t=0

  for(int t=0; t<T_; ++t){
    const float4 gq = gq_nxt;
    // stage H_t (16 KB)
    const u16* Hin = Hbase + (t & 1)*8192;
    #pragma unroll
    for(int r=0; r<2; ++r)
      gload16(Hin + (r*8 + w)*512 + l*8, &Hl[(r*8 + w)*512]);
    __syncthreads();

    f32x4 acc = f32x4{0.f,0.f,0.f,0.f};
    #pragma unroll
    for(int kk=0; kk<16; ++kk){
      const int ke = kk*32 + hi*8;
      bf16x8 bb = *(const bf16x8*)&Hl[(bl << 9) + (ke ^ hswz)];
      acc = __builtin_amdgcn_mfma_f32_16x16x32_bf16(wreg[kk], bb, acc, 0, 0, 0);
    }

    // prefetch gq for t+1 NOW — completes inside the barrier window
    if(t+1 < T_)
      gq_nxt = *(const float4*)&Gq[(long)(t+1)*(4*2048*16) + gqbase];

    const float a0 = acc[0] + gq.x;
    const float a1 = acc[1] + gq.y;
    const float a2 = acc[2] + gq.z;
    const float a3 = acc[3] + gq.w;
    const float ig = 1.f/(1.f + expf(-a0));
    const float fg = 1.f/(1.f + expf(-a1));
    const float gg = tanhf(a2);
    const float og = 1.f/(1.f + expf(-a3));
    cst = fg*cst + ig*gg;
    const float h = og*tanhf(cst);
    u16* Hout = Hbase + ((t+1) & 1)*8192;
    Hout[(bl << 9) + (ug ^ hswz)] = f2bf(h);
    if(sl == t) act[bg*U_ + ug] = h;

    if(t == T_-1) break;
    __syncthreads();                    // drain all waves' h stores
    if(tid == 0)
      __hip_atomic_store(&flagv[(grp*16 + s)*32], (u32)(t+1),
                         __ATOMIC_RELEASE, __HIP_MEMORY_SCOPE_AGENT);
    if(w == 0){
      while(__hip_atomic_load(&flagv[fi], __ATOMIC_ACQUIRE,
                              __HIP_MEMORY_SCOPE_AGENT) <= (u32)t){
        __builtin_amdgcn_s_sleep(1);
      }
    }
    __syncthreads();
  }
}

// ---------------- out[b][n] = sigmoid(actual[b] . sWt[:,n])  (f32 out) ----------------
__global__ void k_score(const float* __restrict__ actual, const u16* __restrict__ sWt,
                        float* __restrict__ out){
  const int n = blockIdx.x*256 + threadIdx.x;
  const int b = blockIdx.y;
  const float* ab = actual + (long)b*U_;
  float s = 0.f;
  for(int uu=0; uu<U_; uu++) s += ab[uu]*bf2f(sWt[(long)uu*N_ + n]);
  out[(long)b*N_ + n] = 1.f/(1.f + expf(-s));
}

extern "C" void kernel_launch(void* const* d_in, const int* in_sizes, int n_in,
                              void* d_out, int out_size, void* d_ws, size_t ws_size,
                              hipStream_t stream){
  (void)in_sizes; (void)n_in; (void)out_size; (void)ws_size;
  const float* A      = (const float*)d_in[0];
  const float* X      = (const float*)d_in[1];
  const float* seqs   = (const float*)d_in[2];
  const int*   seqlen = (const int*)d_in[3];
  const float* h0     = (const float*)d_in[4];
  const float* c0     = (const float*)d_in[5];
  const float* gtw1   = (const float*)d_in[6];
  const float* gtw2   = (const float*)d_in[7];
  const float* gtw3   = (const float*)d_in[8];
  const float* gcnW   = (const float*)d_in[9];
  const float* gcnB   = (const float*)d_in[10];
  const float* lin1W  = (const float*)d_in[11];
  const float* lin1B  = (const float*)d_in[12];
  const float* Wih    = (const float*)d_in[13];
  const float* Whh    = (const float*)d_in[14];
  const float* bihp   = (const float*)d_in[15];
  const float* bhhp   = (const float*)d_in[16];
  const float* scoreW = (const float*)d_in[17];

  char* ws = (char*)d_ws;
  u16* buf0 = (u16*)(ws + 0);
  u16* buf1 = (u16*)(ws + 16777216);
  u16* buf2 = (u16*)(ws + 33554432);
  char* S0  = ws + 50331648;
  float* filt  = (float*)(S0 + 0);
  float* disv  = (float*)(S0 + 1024);
  u16*  Wt     = (u16*) (S0 + 17408);
  u16*  XWt    = (u16*) (S0 + 148480);
  u16*  catb   = (u16*) (S0 + 1197056);
  u16*  l1Wt   = (u16*) (S0 + 3294208);
  float* Xo    = (float*)(S0 + 3556352);
  u16*  bs     = (u16*) (S0 + 5653504);
  float* act   = (float*)(S0 + 7357440);
  u16*  sWt    = (u16*) (S0 + 7488512);
  u16*  WhhB   = (u16*) (S0 + 9585664);
  u16*  Xbf    = (u16*) (S0 + 11682816);
  u16*  Wihbf  = (u16*) (S0 + 12731392);
  float* bsum  = (float*)(S0 + 13779968);
  u16*  Hglob  = (u16*) (S0 + 13788160);
  u32*  flagv  = (u32*) (S0 + 13919232);
  float* degp  = (float*)(S0 + 14050304);
  float* dinvb = (float*)(S0 + 14312448);
  u16* HA   = buf0;
  u16* HBt  = buf1;
  u16* Hb   = buf2;
  u16* HB2t = buf0;
  u16* H2t  = buf1;
  u16* Pd   = buf1;
  float* Gq = (float*)ws;

  k_prep0<<<dim3(8), 256, 0, stream>>>(gtw1, gtw2, gtw3, filt, bihp, bhhp, bsum, flagv);
  k_combineAll<<<dim3(N_/32, N_/32), dim3(32,8), 0, stream>>>(A, filt, HA, HBt);
  k_transpose3<<<dim3(16, 64, 3), dim3(32,8), 0, stream>>>(gcnW, Wt, lin1W, l1Wt, scoreW, sWt);
  k_cast2<<<dim3(4096), 256, 0, stream>>>(X, Xbf, Wih, Wihbf);
  gemm_bt<1><<<dim3(16,16,C_), 256, 0, stream>>>(HA, HBt, Hb, N_, N_, NN_, NN_, NN_, nullptr, 0, nullptr);
  k_degpart<<<dim3(8, 16, C_), 256, 0, stream>>>(Hb, degp);
  k_dinv<<<dim3(16), 256, 0, stream>>>(Hb, degp, dinvb);
  k_colscale<<<dim3(NN_/256, C_), 256, 0, stream>>>(Hb, dinvb);
  k_combineT2<<<dim3(N_/32, N_/32), dim3(32,8), 0, stream>>>(A, filt + 2*C_*E_, HB2t);
  gemm_bt<1><<<dim3(16,16,C_), 256, 0, stream>>>(HB2t, Hb, H2t, N_, N_, NN_, NN_, NN_, nullptr, 0, nullptr);
  k_gcnprep<<<dim3(N_, C_), 256, 0, stream>>>(H2t, disv);
  k_pd<<<dim3(NN_/256, C_), 256, 0, stream>>>(H2t, disv, Pd);
  gemm_bt<1><<<dim3(N_/128, WOUT_/128, 1), 256, 0, stream>>>(Wt, Xbf, XWt, WIN_, N_, 0, 0, 0, nullptr, 0, nullptr);
  gemm_bt<2><<<dim3(WOUT_/128, N_/128, C_), 256, 0, stream>>>(Pd, XWt, catb, N_, C_*WOUT_, NN_, 0, WOUT_, disv, N_, gcnB);
  gemm_bt<3><<<dim3(WOUT_/128, N_/128, 1), 256, 0, stream>>>(catb, l1Wt, Xo, C_*WOUT_, WOUT_, 0, 0, 0, nullptr, 0, lin1B);
  k_pool<<<dim3(52, B_), 256, 0, stream>>>(seqs, Xo, bs);
  gemm_bt<4><<<dim3((4*U_)/128, BTP_/128, 1), 256, 0, stream>>>(bs, Wihbf, Gq, WOUT_, 0, 0, 0, 0, nullptr, 0, bsum);
  k_packWhh3<<<dim3(4096), 256, 0, stream>>>(Whh, WhhB);
  k_hinit<<<dim3(128), 256, 0, stream>>>(h0, Hglob);
  k_lstm_all<<<dim3(64), 512, 0, stream>>>(WhhB, Gq, c0, seqlen, Hglob, flagv, act);
  k_score<<<dim3(N_/256, B_), 256, 0, stream>>>(act, sWt, (float*)d_out);
}